// Round 1
// baseline (100.654 us; speedup 1.0000x reference)
//
#include <hip/hip_runtime.h>

#define B 16
#define N 1024
#define M 1024
#define TN 32   // rows per block in main pass

// ws layout in floats:
#define WS_F     0                  // F matrices, B*9
#define WS_ROT   144                // rot term per b
#define WS_TRANS 160                // trans term per b
#define WS_MAX   176                // per-b max bits (uint), B
#define WS_ACC   192                // per-b {sum_w, sum_cw, sum_ew, count}, B*4
#define WS_T     256                // T_soa [B][2][N]
#define WS_A     (256 + B*2*N)      // A_soa [B][3][M]

// ---------- kernel 1: per-b pose terms + fundamental matrix + zero accumulators
__global__ void k_pose_F(const float* __restrict__ R_pred, const float* __restrict__ t_pred,
                         const float* __restrict__ R_gt,   const float* __restrict__ t_gt,
                         const float* __restrict__ K, float* __restrict__ ws) {
    int b = threadIdx.x;
    if (b >= B) return;
    // zero per-b accumulators (fresh every launch)
    ((unsigned int*)(ws + WS_MAX))[b] = 0u;
    ws[WS_ACC + 4*b + 0] = 0.f;
    ws[WS_ACC + 4*b + 1] = 0.f;
    ws[WS_ACC + 4*b + 2] = 0.f;
    ws[WS_ACC + 4*b + 3] = 0.f;

    const float* Rp = R_pred + b*9;
    const float* Rg = R_gt   + b*9;
    float trace = 0.f;
    #pragma unroll
    for (int i = 0; i < 9; ++i) trace += Rp[i] * Rg[i];
    float geo = (trace - 1.f) * 0.5f;
    geo = fminf(fmaxf(geo, -1.f + 1e-7f), 1.f - 1e-7f);
    ws[WS_ROT + b] = 1.f - geo;

    const float* tg = t_gt + b*3;
    const float* tp = t_pred + b*3;
    float nrm = sqrtf(tg[0]*tg[0] + tg[1]*tg[1] + tg[2]*tg[2]);
    float tx = tg[0]/nrm, ty = tg[1]/nrm, tz = tg[2]/nrm;
    ws[WS_TRANS + b] = 1.f - (tp[0]*tx + tp[1]*ty + tp[2]*tz);

    // E = skew(t_n) @ Rg ; skew rows: [0,-tz,ty],[tz,0,-tx],[-ty,tx,0]
    float E[3][3];
    #pragma unroll
    for (int c = 0; c < 3; ++c) {
        E[0][c] = -tz*Rg[3+c] + ty*Rg[6+c];
        E[1][c] =  tz*Rg[0+c] - tx*Rg[6+c];
        E[2][c] = -ty*Rg[0+c] + tx*Rg[3+c];
    }
    // K_inv via adjugate
    const float* Km = K + b*9;
    float m00=Km[0], m01=Km[1], m02=Km[2];
    float m10=Km[3], m11=Km[4], m12=Km[5];
    float m20=Km[6], m21=Km[7], m22=Km[8];
    float c00 =  (m11*m22 - m12*m21);
    float c01 = -(m10*m22 - m12*m20);
    float c02 =  (m10*m21 - m11*m20);
    float c10 = -(m01*m22 - m02*m21);
    float c11 =  (m00*m22 - m02*m20);
    float c12 = -(m00*m21 - m01*m20);
    float c20 =  (m01*m12 - m02*m11);
    float c21 = -(m00*m12 - m02*m10);
    float c22 =  (m00*m11 - m01*m10);
    float det = m00*c00 + m01*c01 + m02*c02;
    float id = 1.f / det;
    float Ki[3][3] = {{c00*id, c10*id, c20*id},
                      {c01*id, c11*id, c21*id},
                      {c02*id, c12*id, c22*id}};
    // Tmp = E @ Ki ; F = Ki^T @ Tmp
    float Tmp[3][3];
    #pragma unroll
    for (int j = 0; j < 3; ++j)
        #pragma unroll
        for (int l = 0; l < 3; ++l)
            Tmp[j][l] = E[j][0]*Ki[0][l] + E[j][1]*Ki[1][l] + E[j][2]*Ki[2][l];
    #pragma unroll
    for (int i = 0; i < 3; ++i)
        #pragma unroll
        for (int l = 0; l < 3; ++l)
            ws[WS_F + b*9 + i*3 + l] = Ki[0][i]*Tmp[0][l] + Ki[1][i]*Tmp[1][l] + Ki[2][i]*Tmp[2][l];
}

// ---------- kernel 2: precompute T (per-n) and A (per-m) factors
__global__ void k_precompute(const float* __restrict__ R_gt, const float* __restrict__ kp1,
                             const float* __restrict__ kp2, float* __restrict__ ws) {
    int b = blockIdx.x;
    const float* Rg = R_gt + b*9;
    const float* Fm = ws + WS_F + b*9;   // F[k][l] at Fm[k*3+l]
    float* T = ws + WS_T + b*2*N;
    float* A = ws + WS_A + b*3*M;
    for (int n = threadIdx.x; n < N; n += blockDim.x) {
        float x = kp1[(b*N + n)*2 + 0], y = kp1[(b*N + n)*2 + 1];
        T[n]     = Rg[0]*x + Rg[1]*y + Rg[2];
        T[N + n] = Rg[3]*x + Rg[4]*y + Rg[5];
    }
    for (int m = threadIdx.x; m < M; m += blockDim.x) {
        float x = kp2[(b*M + m)*2 + 0], y = kp2[(b*M + m)*2 + 1];
        A[m]       = Fm[0]*x + Fm[3]*y + Fm[6];
        A[M + m]   = Fm[1]*x + Fm[4]*y + Fm[7];
        A[2*M + m] = Fm[2]*x + Fm[5]*y + Fm[8];
    }
}

// ---------- kernel 3: per-b max of matches
__global__ void k_max(const float* __restrict__ matches, float* __restrict__ ws) {
    int b     = blockIdx.x >> 6;   // 64 blocks per b
    int chunk = blockIdx.x & 63;
    const float4* m4 = (const float4*)matches;
    long base = (long)b * (N*M/4) + (long)chunk * (N*M/4/64);
    float v = 0.f;
    #pragma unroll
    for (int i = 0; i < 16; ++i) {
        float4 q = m4[base + i*256 + threadIdx.x];
        v = fmaxf(v, fmaxf(fmaxf(q.x, q.y), fmaxf(q.z, q.w)));
    }
    for (int off = 32; off; off >>= 1) v = fmaxf(v, __shfl_down(v, off));
    __shared__ float wmax[4];
    int lane = threadIdx.x & 63, wid = threadIdx.x >> 6;
    if (lane == 0) wmax[wid] = v;
    __syncthreads();
    if (threadIdx.x == 0) {
        v = fmaxf(fmaxf(wmax[0], wmax[1]), fmaxf(wmax[2], wmax[3]));
        atomicMax((unsigned int*)(ws + WS_MAX) + b, __float_as_uint(v));  // values >= 0
    }
}

// ---------- kernel 4: fused masked weighted sums of corr_err and epi_err
__launch_bounds__(256)
__global__ void k_main(const float* __restrict__ matches, const float* __restrict__ kp1,
                       const float* __restrict__ kp2, float* __restrict__ ws) {
    int b    = blockIdx.x >> 5;        // N/TN = 32 tiles per b
    int tile = blockIdx.x & 31;
    int n0   = tile * TN;
    int t    = threadIdx.x;

    float thr = 0.1f * __uint_as_float(((const unsigned int*)(ws + WS_MAX))[b]);

    __shared__ float sTx[TN], sTy[TN], sP1x[TN], sP1y[TN];
    const float* T = ws + WS_T + b*2*N;
    if (t < TN) { sTx[t] = T[n0 + t]; sTy[t] = T[N + n0 + t]; }
    if (t >= TN && t < 2*TN) {
        int i = t - TN;
        sP1x[i] = kp1[(b*N + n0 + i)*2 + 0];
        sP1y[i] = kp1[(b*N + n0 + i)*2 + 1];
    }

    // per-m data: thread t owns columns m0..m0+3
    const float4* kp2v = (const float4*)(kp2 + b*M*2);
    float4 q0 = kp2v[t*2], q1 = kp2v[t*2 + 1];
    float k2x[4] = {q0.x, q0.z, q1.x, q1.z};
    float k2y[4] = {q0.y, q0.w, q1.y, q1.w};
    const float4* Av = (const float4*)(ws + WS_A + b*3*M);
    float4 a0 = Av[t], a1 = Av[M/4 + t], a2 = Av[2*(M/4) + t];
    float A0[4] = {a0.x, a0.y, a0.z, a0.w};
    float A1[4] = {a1.x, a1.y, a1.z, a1.w};
    float A2[4] = {a2.x, a2.y, a2.z, a2.w};
    __syncthreads();

    const float4* m4 = (const float4*)matches + (long)(b*N + n0) * (M/4);
    float s_w = 0.f, s_c = 0.f, s_e = 0.f, s_n = 0.f;
    for (int n = 0; n < TN; ++n) {
        float4 mv = m4[n*(M/4) + t];
        float Tx = sTx[n], Ty = sTy[n], px = sP1x[n], py = sP1y[n];
        float mvv[4] = {mv.x, mv.y, mv.z, mv.w};
        #pragma unroll
        for (int j = 0; j < 4; ++j) {
            float w = mvv[j];
            bool pass = w > thr;
            float ww = pass ? w : 0.f;
            s_n += pass ? 1.f : 0.f;
            float dx = k2x[j] - Tx, dy = k2y[j] - Ty;
            float ce = sqrtf(dx*dx + dy*dy);
            float ee = fabsf(A0[j]*px + A1[j]*py + A2[j]);
            s_w += ww;
            s_c += ce * ww;
            s_e += ee * ww;
        }
    }
    for (int off = 32; off; off >>= 1) {
        s_w += __shfl_down(s_w, off);
        s_c += __shfl_down(s_c, off);
        s_e += __shfl_down(s_e, off);
        s_n += __shfl_down(s_n, off);
    }
    if ((t & 63) == 0) {
        float* acc = ws + WS_ACC + b*4;
        atomicAdd(acc + 0, s_w);
        atomicAdd(acc + 1, s_c);
        atomicAdd(acc + 2, s_e);
        atomicAdd(acc + 3, s_n);
    }
}

// ---------- kernel 5: final combine
__global__ void k_final(const float* __restrict__ ws, float* __restrict__ out) {
    if (threadIdx.x != 0) return;
    float rot = 0.f, tr = 0.f, ms = 0.f, es = 0.f;
    int nv = 0;
    for (int b = 0; b < B; ++b) {
        rot += ws[WS_ROT + b];
        tr  += ws[WS_TRANS + b];
        float sw = ws[WS_ACC + 4*b + 0];
        float sc = ws[WS_ACC + 4*b + 1];
        float se = ws[WS_ACC + 4*b + 2];
        float cn = ws[WS_ACC + 4*b + 3];
        if (cn >= 3.f) { nv++; ms += sc / (sw + 1e-8f); es += se / (sw + 1e-8f); }
    }
    float match = nv > 0 ? ms / (float)nv : 0.f;
    float epi   = nv > 0 ? es / (float)nv : 0.f;
    out[0] = (rot + tr) * (1.f / (float)B) + 0.5f * match + 0.1f * epi;
}

extern "C" void kernel_launch(void* const* d_in, const int* in_sizes, int n_in,
                              void* d_out, int out_size, void* d_ws, size_t ws_size,
                              hipStream_t stream) {
    const float* R_pred  = (const float*)d_in[0];
    const float* t_pred  = (const float*)d_in[1];
    const float* R_gt    = (const float*)d_in[2];
    const float* t_gt    = (const float*)d_in[3];
    const float* K       = (const float*)d_in[4];
    const float* kp1     = (const float*)d_in[5];
    const float* kp2     = (const float*)d_in[6];
    const float* matches = (const float*)d_in[7];
    float* out = (float*)d_out;
    float* ws  = (float*)d_ws;

    k_pose_F<<<1, 64, 0, stream>>>(R_pred, t_pred, R_gt, t_gt, K, ws);
    k_precompute<<<B, 256, 0, stream>>>(R_gt, kp1, kp2, ws);
    k_max<<<B*64, 256, 0, stream>>>(matches, ws);
    k_main<<<B*(N/TN), 256, 0, stream>>>(matches, kp1, kp2, ws);
    k_final<<<1, 64, 0, stream>>>(ws, out);
}

// Round 2
// 65.484 us; speedup vs baseline: 1.5371x; 1.5371x over previous
//
#include <hip/hip_runtime.h>

#define B 16
#define N 1024
#define M 1024
#define TN 8                 // rows per block in max/main passes
#define NBLK (B * (N / TN))  // 2048 blocks for both big passes

// ws layout in floats:
#define WS_PMAX  0            // per-block max, NBLK
#define WS_ROT   2048         // per-b rot term, B
#define WS_TRANS 2064         // per-b trans term, B
#define WS_F     2080         // F matrices, B*9
#define WS_PACC  2240         // per-block {sum_w,sum_cw,sum_ew,count}, NBLK*4 (float4-aligned)
#define WS_T     10432        // T_soa [B][2][N]
#define WS_A     (10432 + B*2*N)  // A_soa [B][3][M]

// ---------- kernel 1: per-block max of matches (no atomics, pure overwrite)
__launch_bounds__(256, 8)
__global__ void k_max(const float* __restrict__ matches, float* __restrict__ ws) {
    int bid = blockIdx.x;          // covers rows [bid*TN, bid*TN+TN)
    int t = threadIdx.x;
    const float4* m4 = (const float4*)matches + (long)bid * (TN * (M / 4));
    float v = 0.f;
    #pragma unroll
    for (int n = 0; n < TN; ++n) {
        float4 q = m4[n * (M / 4) + t];
        v = fmaxf(v, fmaxf(fmaxf(q.x, q.y), fmaxf(q.z, q.w)));
    }
    #pragma unroll
    for (int off = 32; off; off >>= 1) v = fmaxf(v, __shfl_down(v, off));
    __shared__ float sm[4];
    if ((t & 63) == 0) sm[t >> 6] = v;
    __syncthreads();
    if (t == 0)
        ws[WS_PMAX + bid] = fmaxf(fmaxf(sm[0], sm[1]), fmaxf(sm[2], sm[3]));
}

// ---------- kernel 2: pose terms + fundamental matrix + T/A factor precompute
__global__ void k_prep(const float* __restrict__ R_pred, const float* __restrict__ t_pred,
                       const float* __restrict__ R_gt,   const float* __restrict__ t_gt,
                       const float* __restrict__ K, const float* __restrict__ kp1,
                       const float* __restrict__ kp2, float* __restrict__ ws) {
    int b = blockIdx.x;
    int t = threadIdx.x;
    __shared__ float sF[9];

    if (t == 0) {
        const float* Rp = R_pred + b*9;
        const float* Rg = R_gt   + b*9;
        float trace = 0.f;
        #pragma unroll
        for (int i = 0; i < 9; ++i) trace += Rp[i] * Rg[i];
        float geo = (trace - 1.f) * 0.5f;
        geo = fminf(fmaxf(geo, -1.f + 1e-7f), 1.f - 1e-7f);
        ws[WS_ROT + b] = 1.f - geo;

        const float* tg = t_gt + b*3;
        const float* tp = t_pred + b*3;
        float nrm = sqrtf(tg[0]*tg[0] + tg[1]*tg[1] + tg[2]*tg[2]);
        float tx = tg[0]/nrm, ty = tg[1]/nrm, tz = tg[2]/nrm;
        ws[WS_TRANS + b] = 1.f - (tp[0]*tx + tp[1]*ty + tp[2]*tz);

        float E[3][3];
        #pragma unroll
        for (int c = 0; c < 3; ++c) {
            E[0][c] = -tz*Rg[3+c] + ty*Rg[6+c];
            E[1][c] =  tz*Rg[0+c] - tx*Rg[6+c];
            E[2][c] = -ty*Rg[0+c] + tx*Rg[3+c];
        }
        const float* Km = K + b*9;
        float m00=Km[0], m01=Km[1], m02=Km[2];
        float m10=Km[3], m11=Km[4], m12=Km[5];
        float m20=Km[6], m21=Km[7], m22=Km[8];
        float c00 =  (m11*m22 - m12*m21);
        float c01 = -(m10*m22 - m12*m20);
        float c02 =  (m10*m21 - m11*m20);
        float c10 = -(m01*m22 - m02*m21);
        float c11 =  (m00*m22 - m02*m20);
        float c12 = -(m00*m21 - m01*m20);
        float c20 =  (m01*m12 - m02*m11);
        float c21 = -(m00*m12 - m02*m10);
        float c22 =  (m00*m11 - m01*m10);
        float det = m00*c00 + m01*c01 + m02*c02;
        float id = 1.f / det;
        float Ki[3][3] = {{c00*id, c10*id, c20*id},
                          {c01*id, c11*id, c21*id},
                          {c02*id, c12*id, c22*id}};
        float Tmp[3][3];
        #pragma unroll
        for (int j = 0; j < 3; ++j)
            #pragma unroll
            for (int l = 0; l < 3; ++l)
                Tmp[j][l] = E[j][0]*Ki[0][l] + E[j][1]*Ki[1][l] + E[j][2]*Ki[2][l];
        #pragma unroll
        for (int i = 0; i < 3; ++i)
            #pragma unroll
            for (int l = 0; l < 3; ++l) {
                float f = Ki[0][i]*Tmp[0][l] + Ki[1][i]*Tmp[1][l] + Ki[2][i]*Tmp[2][l];
                sF[i*3 + l] = f;
                ws[WS_F + b*9 + i*3 + l] = f;
            }
    }
    __syncthreads();

    const float* Rg = R_gt + b*9;
    float* T = ws + WS_T + b*2*N;
    float* A = ws + WS_A + b*3*M;
    for (int n = t; n < N; n += 256) {
        float x = kp1[(b*N + n)*2 + 0], y = kp1[(b*N + n)*2 + 1];
        T[n]     = Rg[0]*x + Rg[1]*y + Rg[2];
        T[N + n] = Rg[3]*x + Rg[4]*y + Rg[5];
    }
    for (int m = t; m < M; m += 256) {
        float x = kp2[(b*M + m)*2 + 0], y = kp2[(b*M + m)*2 + 1];
        A[m]       = sF[0]*x + sF[3]*y + sF[6];
        A[M + m]   = sF[1]*x + sF[4]*y + sF[7];
        A[2*M + m] = sF[2]*x + sF[5]*y + sF[8];
    }
}

// ---------- kernel 3: fused masked weighted sums (per-block partials, no atomics)
__launch_bounds__(256, 8)
__global__ void k_main(const float* __restrict__ matches, const float* __restrict__ kp1,
                       const float* __restrict__ kp2, float* __restrict__ ws) {
    int bid  = blockIdx.x;
    int b    = bid >> 7;          // 128 tiles per b
    int n0   = (bid & 127) * TN;
    int t    = threadIdx.x;
    int w    = t >> 6, lane = t & 63;

    // reduce this b's 128 per-block maxes (L2-hot, 512B)
    float pv = ws[WS_PMAX + b*128 + ((w & 1) << 6) + lane];
    #pragma unroll
    for (int off = 32; off; off >>= 1) pv = fmaxf(pv, __shfl_down(pv, off));
    __shared__ float sm[4];
    if (lane == 0) sm[w] = pv;

    __shared__ float sTx[TN], sTy[TN], sP1x[TN], sP1y[TN];
    const float* T = ws + WS_T + b*2*N;
    if (t < TN) { sTx[t] = T[n0 + t]; sTy[t] = T[N + n0 + t]; }
    if (t >= 64 && t < 64 + TN) {
        int i = t - 64;
        sP1x[i] = kp1[(b*N + n0 + i)*2 + 0];
        sP1y[i] = kp1[(b*N + n0 + i)*2 + 1];
    }

    // per-m data: thread t owns columns 4t..4t+3
    const float4* kp2v = (const float4*)(kp2 + b*M*2);
    float4 q0 = kp2v[t*2], q1 = kp2v[t*2 + 1];
    float k2x[4] = {q0.x, q0.z, q1.x, q1.z};
    float k2y[4] = {q0.y, q0.w, q1.y, q1.w};
    const float4* Av = (const float4*)(ws + WS_A + b*3*M);
    float4 a0 = Av[t], a1 = Av[M/4 + t], a2 = Av[2*(M/4) + t];
    float A0[4] = {a0.x, a0.y, a0.z, a0.w};
    float A1[4] = {a1.x, a1.y, a1.z, a1.w};
    float A2[4] = {a2.x, a2.y, a2.z, a2.w};
    __syncthreads();

    float thr = 0.1f * fmaxf(fmaxf(sm[0], sm[1]), fmaxf(sm[2], sm[3]));

    const float4* m4 = (const float4*)matches + (long)bid * (TN * (M / 4));
    float s_w = 0.f, s_c = 0.f, s_e = 0.f, s_n = 0.f;
    #pragma unroll
    for (int n = 0; n < TN; ++n) {
        float4 mv = m4[n * (M / 4) + t];
        float Tx = sTx[n], Ty = sTy[n], px = sP1x[n], py = sP1y[n];
        float mvv[4] = {mv.x, mv.y, mv.z, mv.w};
        #pragma unroll
        for (int j = 0; j < 4; ++j) {
            float wgt = mvv[j];
            bool pass = wgt > thr;
            float ww = pass ? wgt : 0.f;
            s_n += pass ? 1.f : 0.f;
            float dx = k2x[j] - Tx, dy = k2y[j] - Ty;
            float ce = sqrtf(dx*dx + dy*dy);
            float ee = fabsf(A0[j]*px + A1[j]*py + A2[j]);
            s_w += ww;
            s_c += ce * ww;
            s_e += ee * ww;
        }
    }
    #pragma unroll
    for (int off = 32; off; off >>= 1) {
        s_w += __shfl_down(s_w, off);
        s_c += __shfl_down(s_c, off);
        s_e += __shfl_down(s_e, off);
        s_n += __shfl_down(s_n, off);
    }
    __shared__ float4 pacc[4];
    if (lane == 0) pacc[w] = make_float4(s_w, s_c, s_e, s_n);
    __syncthreads();
    if (t == 0) {
        float4 r = pacc[0];
        #pragma unroll
        for (int i = 1; i < 4; ++i) {
            r.x += pacc[i].x; r.y += pacc[i].y; r.z += pacc[i].z; r.w += pacc[i].w;
        }
        ((float4*)(ws + WS_PACC))[bid] = r;
    }
}

// ---------- kernel 4: final reduce + combine
__global__ void k_final(const float* __restrict__ ws, float* __restrict__ out) {
    int t = threadIdx.x;            // 256 threads: b = t>>4, i = t&15
    int b = t >> 4, i = t & 15;
    float4 acc = make_float4(0.f, 0.f, 0.f, 0.f);
    const float4* pacc = (const float4*)(ws + WS_PACC);
    for (int j = i; j < 128; j += 16) {
        float4 r = pacc[b*128 + j];
        acc.x += r.x; acc.y += r.y; acc.z += r.z; acc.w += r.w;
    }
    #pragma unroll
    for (int off = 8; off; off >>= 1) {
        acc.x += __shfl_down(acc.x, off);
        acc.y += __shfl_down(acc.y, off);
        acc.z += __shfl_down(acc.z, off);
        acc.w += __shfl_down(acc.w, off);
    }
    __shared__ float4 sb[16];
    if (i == 0) sb[b] = acc;
    __syncthreads();
    if (t == 0) {
        float rot = 0.f, tr = 0.f, ms = 0.f, es = 0.f;
        int nv = 0;
        for (int bb = 0; bb < B; ++bb) {
            rot += ws[WS_ROT + bb];
            tr  += ws[WS_TRANS + bb];
            float4 r = sb[bb];
            if (r.w >= 3.f) { nv++; ms += r.y / (r.x + 1e-8f); es += r.z / (r.x + 1e-8f); }
        }
        float match = nv > 0 ? ms / (float)nv : 0.f;
        float epi   = nv > 0 ? es / (float)nv : 0.f;
        out[0] = (rot + tr) * (1.f / (float)B) + 0.5f * match + 0.1f * epi;
    }
}

extern "C" void kernel_launch(void* const* d_in, const int* in_sizes, int n_in,
                              void* d_out, int out_size, void* d_ws, size_t ws_size,
                              hipStream_t stream) {
    const float* R_pred  = (const float*)d_in[0];
    const float* t_pred  = (const float*)d_in[1];
    const float* R_gt    = (const float*)d_in[2];
    const float* t_gt    = (const float*)d_in[3];
    const float* K       = (const float*)d_in[4];
    const float* kp1     = (const float*)d_in[5];
    const float* kp2     = (const float*)d_in[6];
    const float* matches = (const float*)d_in[7];
    float* out = (float*)d_out;
    float* ws  = (float*)d_ws;

    k_max <<<NBLK, 256, 0, stream>>>(matches, ws);
    k_prep<<<B,    256, 0, stream>>>(R_pred, t_pred, R_gt, t_gt, K, kp1, kp2, ws);
    k_main<<<NBLK, 256, 0, stream>>>(matches, kp1, kp2, ws);
    k_final<<<1,   256, 0, stream>>>(ws, out);
}

// Round 3
// 45.091 us; speedup vs baseline: 2.2322x; 1.4523x over previous
//
#include <hip/hip_runtime.h>

#define B 16
#define N 1024
#define M 1024
#define TN 8                 // rows per block in max/main passes
#define NBLK (B * (N / TN))  // 2048 blocks for both big passes

// ws layout in floats (total 92224 floats = 369 KB):
#define WS_PMAX  0            // per-block max, NBLK
#define WS_ROT   2048         // per-b rot term, B
#define WS_TRANS 2064         // per-b trans term, B
#define WS_THR   2080         // per-b 0.1*max, B (padded to 2112)
#define WS_PACC  2112         // per-block {sum_w,sum_cw,sum_ew,count}, NBLK*4
#define WS_T     10304        // T interleaved [B][N][2]
#define WS_A     43072        // A_soa [B][3][M]

// ---------- kernel 1: per-block max of matches (no atomics, pure overwrite)
__launch_bounds__(256, 8)
__global__ void k_max(const float* __restrict__ matches, float* __restrict__ ws) {
    int bid = blockIdx.x;
    int t = threadIdx.x;
    const float4* m4 = (const float4*)matches + (long)bid * (TN * (M / 4)) + t;
    float4 d[TN];
    #pragma unroll
    for (int n = 0; n < TN; ++n) d[n] = m4[n * (M / 4)];
    float v = 0.f;
    #pragma unroll
    for (int n = 0; n < TN; ++n)
        v = fmaxf(v, fmaxf(fmaxf(d[n].x, d[n].y), fmaxf(d[n].z, d[n].w)));
    #pragma unroll
    for (int off = 32; off; off >>= 1) v = fmaxf(v, __shfl_down(v, off));
    __shared__ float sm[4];
    if ((t & 63) == 0) sm[t >> 6] = v;
    __syncthreads();
    if (t == 0)
        ws[WS_PMAX + bid] = fmaxf(fmaxf(sm[0], sm[1]), fmaxf(sm[2], sm[3]));
}

// ---------- kernel 2: pose terms + F + T/A precompute + per-b threshold
__global__ void k_prep(const float* __restrict__ R_pred, const float* __restrict__ t_pred,
                       const float* __restrict__ R_gt,   const float* __restrict__ t_gt,
                       const float* __restrict__ K, const float* __restrict__ kp1,
                       const float* __restrict__ kp2, float* __restrict__ ws) {
    int b = blockIdx.x;
    int t = threadIdx.x;
    __shared__ float sF[9];

    // wave 0: reduce this b's 128 per-block maxes -> threshold
    if (t < 64) {
        float pv = fmaxf(ws[WS_PMAX + b*128 + t], ws[WS_PMAX + b*128 + 64 + t]);
        #pragma unroll
        for (int off = 32; off; off >>= 1) pv = fmaxf(pv, __shfl_down(pv, off));
        if (t == 0) ws[WS_THR + b] = 0.1f * pv;
    }

    if (t == 0) {
        const float* Rp = R_pred + b*9;
        const float* Rg = R_gt   + b*9;
        float trace = 0.f;
        #pragma unroll
        for (int i = 0; i < 9; ++i) trace += Rp[i] * Rg[i];
        float geo = (trace - 1.f) * 0.5f;
        geo = fminf(fmaxf(geo, -1.f + 1e-7f), 1.f - 1e-7f);
        ws[WS_ROT + b] = 1.f - geo;

        const float* tg = t_gt + b*3;
        const float* tp = t_pred + b*3;
        float nrm = sqrtf(tg[0]*tg[0] + tg[1]*tg[1] + tg[2]*tg[2]);
        float tx = tg[0]/nrm, ty = tg[1]/nrm, tz = tg[2]/nrm;
        ws[WS_TRANS + b] = 1.f - (tp[0]*tx + tp[1]*ty + tp[2]*tz);

        float E[3][3];
        #pragma unroll
        for (int c = 0; c < 3; ++c) {
            E[0][c] = -tz*Rg[3+c] + ty*Rg[6+c];
            E[1][c] =  tz*Rg[0+c] - tx*Rg[6+c];
            E[2][c] = -ty*Rg[0+c] + tx*Rg[3+c];
        }
        const float* Km = K + b*9;
        float m00=Km[0], m01=Km[1], m02=Km[2];
        float m10=Km[3], m11=Km[4], m12=Km[5];
        float m20=Km[6], m21=Km[7], m22=Km[8];
        float c00 =  (m11*m22 - m12*m21);
        float c01 = -(m10*m22 - m12*m20);
        float c02 =  (m10*m21 - m11*m20);
        float c10 = -(m01*m22 - m02*m21);
        float c11 =  (m00*m22 - m02*m20);
        float c12 = -(m00*m21 - m01*m20);
        float c20 =  (m01*m12 - m02*m11);
        float c21 = -(m00*m12 - m02*m10);
        float c22 =  (m00*m11 - m01*m10);
        float det = m00*c00 + m01*c01 + m02*c02;
        float id = 1.f / det;
        float Ki[3][3] = {{c00*id, c10*id, c20*id},
                          {c01*id, c11*id, c21*id},
                          {c02*id, c12*id, c22*id}};
        float Tmp[3][3];
        #pragma unroll
        for (int j = 0; j < 3; ++j)
            #pragma unroll
            for (int l = 0; l < 3; ++l)
                Tmp[j][l] = E[j][0]*Ki[0][l] + E[j][1]*Ki[1][l] + E[j][2]*Ki[2][l];
        #pragma unroll
        for (int i = 0; i < 3; ++i)
            #pragma unroll
            for (int l = 0; l < 3; ++l)
                sF[i*3 + l] = Ki[0][i]*Tmp[0][l] + Ki[1][i]*Tmp[1][l] + Ki[2][i]*Tmp[2][l];
    }
    __syncthreads();

    const float* Rg = R_gt + b*9;
    float2* T = (float2*)(ws + WS_T) + b*N;
    float* A = ws + WS_A + b*3*M;
    for (int n = t; n < N; n += 256) {
        float x = kp1[(b*N + n)*2 + 0], y = kp1[(b*N + n)*2 + 1];
        float2 r;
        r.x = Rg[0]*x + Rg[1]*y + Rg[2];
        r.y = Rg[3]*x + Rg[4]*y + Rg[5];
        T[n] = r;
    }
    for (int m = t; m < M; m += 256) {
        float x = kp2[(b*M + m)*2 + 0], y = kp2[(b*M + m)*2 + 1];
        A[m]       = sF[0]*x + sF[3]*y + sF[6];
        A[M + m]   = sF[1]*x + sF[4]*y + sF[7];
        A[2*M + m] = sF[2]*x + sF[5]*y + sF[8];
    }
}

// ---------- kernel 3: fused masked weighted sums (MLP-first, per-block partials)
__launch_bounds__(256, 4)
__global__ void k_main(const float* __restrict__ matches, const float* __restrict__ kp1,
                       const float* __restrict__ kp2, float* __restrict__ ws) {
    int bid  = blockIdx.x;
    int b    = bid >> 7;          // 128 tiles per b
    int n0   = (bid & 127) * TN;
    int t    = threadIdx.x;
    int w    = t >> 6, lane = t & 63;

    // issue ALL matches loads first — 8 independent 16B loads in flight per thread
    const float4* m4 = (const float4*)matches + (long)bid * (TN * (M / 4)) + t;
    float4 d[TN];
    #pragma unroll
    for (int n = 0; n < TN; ++n) d[n] = m4[n * (M / 4)];

    // per-row broadcast data via LDS (single barrier)
    __shared__ float2 sT[TN], sP[TN];
    if (t < TN) sT[t] = ((const float2*)(ws + WS_T))[b*N + n0 + t];
    if (t >= 64 && t < 64 + TN) {
        int i = t - 64;
        sP[i] = ((const float2*)kp1)[(long)b*N + n0 + i];
    }

    // per-thread per-m data: thread t owns columns 4t..4t+3
    const float4* kp2v = (const float4*)(kp2 + b*M*2);
    float4 q0 = kp2v[t*2], q1 = kp2v[t*2 + 1];
    float k2x[4] = {q0.x, q0.z, q1.x, q1.z};
    float k2y[4] = {q0.y, q0.w, q1.y, q1.w};
    const float4* Av = (const float4*)(ws + WS_A + b*3*M);
    float4 a0 = Av[t], a1 = Av[M/4 + t], a2 = Av[2*(M/4) + t];
    float A0[4] = {a0.x, a0.y, a0.z, a0.w};
    float A1[4] = {a1.x, a1.y, a1.z, a1.w};
    float A2[4] = {a2.x, a2.y, a2.z, a2.w};

    float thr = ws[WS_THR + b];
    __syncthreads();

    float s_w = 0.f, s_c = 0.f, s_e = 0.f, s_n = 0.f;
    #pragma unroll
    for (int n = 0; n < TN; ++n) {
        float Tx = sT[n].x, Ty = sT[n].y, px = sP[n].x, py = sP[n].y;
        float mvv[4] = {d[n].x, d[n].y, d[n].z, d[n].w};
        #pragma unroll
        for (int j = 0; j < 4; ++j) {
            float wgt = mvv[j];
            bool pass = wgt > thr;
            float ww = pass ? wgt : 0.f;
            s_n += pass ? 1.f : 0.f;
            float dx = k2x[j] - Tx, dy = k2y[j] - Ty;
            float ce = sqrtf(dx*dx + dy*dy);
            float ee = fabsf(A0[j]*px + A1[j]*py + A2[j]);
            s_w += ww;
            s_c += ce * ww;
            s_e += ee * ww;
        }
    }
    #pragma unroll
    for (int off = 32; off; off >>= 1) {
        s_w += __shfl_down(s_w, off);
        s_c += __shfl_down(s_c, off);
        s_e += __shfl_down(s_e, off);
        s_n += __shfl_down(s_n, off);
    }
    __shared__ float4 pacc[4];
    if (lane == 0) pacc[w] = make_float4(s_w, s_c, s_e, s_n);
    __syncthreads();
    if (t == 0) {
        float4 r = pacc[0];
        #pragma unroll
        for (int i = 1; i < 4; ++i) {
            r.x += pacc[i].x; r.y += pacc[i].y; r.z += pacc[i].z; r.w += pacc[i].w;
        }
        ((float4*)(ws + WS_PACC))[bid] = r;
    }
}

// ---------- kernel 4: final reduce + combine
__global__ void k_final(const float* __restrict__ ws, float* __restrict__ out) {
    int t = threadIdx.x;            // 256 threads: b = t>>4, i = t&15
    int b = t >> 4, i = t & 15;
    float4 acc = make_float4(0.f, 0.f, 0.f, 0.f);
    const float4* pacc = (const float4*)(ws + WS_PACC);
    for (int j = i; j < 128; j += 16) {
        float4 r = pacc[b*128 + j];
        acc.x += r.x; acc.y += r.y; acc.z += r.z; acc.w += r.w;
    }
    #pragma unroll
    for (int off = 8; off; off >>= 1) {
        acc.x += __shfl_down(acc.x, off);
        acc.y += __shfl_down(acc.y, off);
        acc.z += __shfl_down(acc.z, off);
        acc.w += __shfl_down(acc.w, off);
    }
    __shared__ float4 sb[16];
    if (i == 0) sb[b] = acc;
    __syncthreads();
    if (t == 0) {
        float rot = 0.f, tr = 0.f, ms = 0.f, es = 0.f;
        int nv = 0;
        for (int bb = 0; bb < B; ++bb) {
            rot += ws[WS_ROT + bb];
            tr  += ws[WS_TRANS + bb];
            float4 r = sb[bb];
            if (r.w >= 3.f) { nv++; ms += r.y / (r.x + 1e-8f); es += r.z / (r.x + 1e-8f); }
        }
        float match = nv > 0 ? ms / (float)nv : 0.f;
        float epi   = nv > 0 ? es / (float)nv : 0.f;
        out[0] = (rot + tr) * (1.f / (float)B) + 0.5f * match + 0.1f * epi;
    }
}

extern "C" void kernel_launch(void* const* d_in, const int* in_sizes, int n_in,
                              void* d_out, int out_size, void* d_ws, size_t ws_size,
                              hipStream_t stream) {
    const float* R_pred  = (const float*)d_in[0];
    const float* t_pred  = (const float*)d_in[1];
    const float* R_gt    = (const float*)d_in[2];
    const float* t_gt    = (const float*)d_in[3];
    const float* K       = (const float*)d_in[4];
    const float* kp1     = (const float*)d_in[5];
    const float* kp2     = (const float*)d_in[6];
    const float* matches = (const float*)d_in[7];
    float* out = (float*)d_out;
    float* ws  = (float*)d_ws;

    k_max <<<NBLK, 256, 0, stream>>>(matches, ws);
    k_prep<<<B,    256, 0, stream>>>(R_pred, t_pred, R_gt, t_gt, K, kp1, kp2, ws);
    k_main<<<NBLK, 256, 0, stream>>>(matches, kp1, kp2, ws);
    k_final<<<1,   256, 0, stream>>>(ws, out);
}